// Round 3
// baseline (999.033 us; speedup 1.0000x reference)
//
#include <hip/hip_runtime.h>

// GPTQ 4-bit quantized linear, MI355X (gfx950). fp32 in/out.
// out[M,N] = x[M,K] @ dequant(qweight)[K,N] + bias[N]
// M=4096, K=4096, N=11008, groupsize=128.
//
// Round 8 = round 7 resubmitted (round 7 died to a container/infra failure;
// audit found no hang/OOB/race path in the kernel -- see session notes).
//  - gemm_8ph: fragment ds_reads software-pipelined one phase ahead (reads
//    for phase i+1 issue during MFMA(i) -> LDS pipe busy during MFMA pipe;
//    the phase rotation means reads(i+1) never touch MFMA(i)'s registers).
//    Entry barriers dropped on non-drain phases (10 barriers/iter vs 16);
//    explicit lgkmcnt(0) removed -- compiler emits exact counted lgkmcnt for
//    its own ds_read->MFMA deps. VMW4 drain points + counts unchanged.
//  - conv_x + dequant_w merged into one `prep` kernel (one launch gap saved;
//    latency-bound dequant overlaps BW-bound conv; also makes phase-1 cost
//    visible in rocprof top-5).

#define TM 4096
#define TK 4096
#define TN 11008
#define GS 128
#define NG (TK / GS)
#define QZC (TN / 8)

// ---- phase-2 geometry (256x256 tile, BK=64, 8 waves / 512 threads) ----
#define BM2 256
#define BN2 256
#define BK2 64
#define NKT (TK / BK2)                    // 64 K-tiles
#define NBN (TN / BN2)                    // 43
#define GRID2 ((TM / BM2) * (TN / BN2))   // 16*43 = 688 (== 0 mod 8)

// ---- prep kernel geometry ----
#define DQB (32 * (TN / 64))              // 5504 dequant blocks
#define CVB (TM * TK / 8 / 256)           // 8192 conv blocks

// ---- legacy 128^2 geometry (fallback kernel) ----
#define BM 128
#define BN 128
#define BK 32

#define XB_BYTES ((size_t)TM * TK * 2)            // 33,554,432
#define WT_BYTES ((size_t)TN * TK * 2)            // 90,177,536
#define WS_NEED  (XB_BYTES + WT_BYTES)

typedef __attribute__((ext_vector_type(8))) short short8;
typedef __attribute__((ext_vector_type(4))) float floatx4;

union S8U { short8 v; unsigned u[4]; };

__device__ __forceinline__ unsigned short f2bf_rn(float f) {
    unsigned u = __builtin_bit_cast(unsigned, f);
    u += 0x7FFFu + ((u >> 16) & 1u);
    return (unsigned short)(u >> 16);
}
__device__ __forceinline__ unsigned pack2(float a, float b) {
    return (unsigned)f2bf_rn(a) | ((unsigned)f2bf_rn(b) << 16);
}

// ---------------- Phase 1 (merged): dequant W^T + convert X ----------------
__global__ __launch_bounds__(256)
void prep(const float* __restrict__ X, unsigned short* __restrict__ Xb,
          const int* __restrict__ QW, const int* __restrict__ QZ,
          const float* __restrict__ SC, unsigned short* __restrict__ Wt)
{
    if (blockIdx.x < DQB) {
        // ---- dequant qweight -> bf16 W^T[N][K] ----
        const int ptile = blockIdx.x % 32;        // 32 p-tiles = 32 groups
        const int ntile = blockIdx.x / 32;        // 172 n-tiles
        const int g  = ptile;
        const int p  = ptile * 16 + (threadIdx.x & 15);
        const int nb = threadIdx.x >> 4;          // 0..15

        #pragma unroll
        for (int i = 0; i < 4; ++i) {
            const int n = ntile * 64 + nb + 16 * i;
            const float s = SC[(size_t)g * TN + n];
            const int z = (int)(((unsigned)QZ[g * QZC + (n >> 3)] >> ((n & 7) * 4)) & 15u) + 1;
            const float zc = -s * (float)z;
            const unsigned q = (unsigned)QW[(size_t)p * TN + n];
            const unsigned qe = q & 0x0F0F0F0Fu;          // nibbles 0,2,4,6
            const unsigned qo = (q >> 4) & 0x0F0F0F0Fu;   // nibbles 1,3,5,7
            S8U vv;
            #pragma unroll
            for (int jj = 0; jj < 4; ++jj) {
                const float w0 = (float)((qe >> (8 * jj)) & 0xFFu);
                const float w1 = (float)((qo >> (8 * jj)) & 0xFFu);
                vv.u[jj] = pack2(fmaf(w0, s, zc), fmaf(w1, s, zc));
            }
            *(short8*)(Wt + (size_t)n * TK + p * 8) = vv.v;
        }
    } else {
        // ---- X fp32 -> bf16 ----
        const size_t bid = blockIdx.x - DQB;
        const size_t i = (bid * 256 + threadIdx.x) * 8;
        floatx4 v0 = *(const floatx4*)(X + i);
        floatx4 v1 = *(const floatx4*)(X + i + 4);
        S8U o;
        o.u[0] = pack2(v0[0], v0[1]); o.u[1] = pack2(v0[2], v0[3]);
        o.u[2] = pack2(v1[0], v1[1]); o.u[3] = pack2(v1[2], v1[3]);
        *(short8*)(Xb + i) = o.v;
    }
}

// ---------------- Phase 2: 256^2 8-phase bf16 GEMM ----------------
#define GLDS(gp, lp) __builtin_amdgcn_global_load_lds( \
    (const __attribute__((address_space(1))) void*)(gp), \
    (__attribute__((address_space(3))) void*)(lp), 16, 0, 0)

// op: 0=A, 1=B. half: 0 = rows [0,128), 1 = rows [128,256).
#define STAGE(op, gptr, buf, half, kt) do {                                   \
    const unsigned short* _g = (gptr) + (size_t)(half) * 128 * TK             \
                                      + (size_t)(kt) * BK2;                   \
    short* _l = &sh[buf][op][(half) * 8192 + ldst];                           \
    GLDS(_g, _l);                                                             \
    GLDS(_g + (size_t)64 * TK, _l + 4096);                                    \
} while (0)

// swizzled fragment reads: global 16B-chunk c sits at LDS slot c ^ (row&7)
#define RDA(buf, mi, ks) (*(const short8*)&sh[buf][0][ \
    (wr * 128 + (mi) * 16 + l16) * 64 + ((((ks) << 2) | quad) ^ swz) * 8])
#define RDB(buf, ni, ks) (*(const short8*)&sh[buf][1][ \
    (wc * 64 + (ni) * 16 + l16) * 64 + ((((ks) << 2) | quad) ^ swz) * 8])

#define RD_A4(dst, buf, mi0) do {                                             \
    _Pragma("unroll")                                                         \
    for (int _m = 0; _m < 4; ++_m) {                                          \
        dst[_m][0] = RDA(buf, (mi0) + _m, 0);                                 \
        dst[_m][1] = RDA(buf, (mi0) + _m, 1);                                 \
    } } while (0)
#define RD_B2(dst, buf, ni0) do {                                             \
    _Pragma("unroll")                                                         \
    for (int _n = 0; _n < 2; ++_n) {                                          \
        dst[_n][0] = RDB(buf, (ni0) + _n, 0);                                 \
        dst[_n][1] = RDB(buf, (ni0) + _n, 1);                                 \
    } } while (0)

#define BARRIER __builtin_amdgcn_s_barrier()
#define SB0     __builtin_amdgcn_sched_barrier(0)
#define VMW4    asm volatile("s_waitcnt vmcnt(4)" ::: "memory")

template<int MI0, int NI0>
__device__ __forceinline__ void mfma_q(floatx4 (&acc)[8][4],
                                       const short8 (&a)[4][2],
                                       const short8 (&b)[2][2]) {
    __builtin_amdgcn_s_setprio(1);
    #pragma unroll
    for (int m = 0; m < 4; ++m)
        #pragma unroll
        for (int n = 0; n < 2; ++n)
            #pragma unroll
            for (int ks = 0; ks < 2; ++ks)
                acc[MI0 + m][NI0 + n] = __builtin_amdgcn_mfma_f32_16x16x32_bf16(
                    a[m][ks], b[n][ks], acc[MI0 + m][NI0 + n], 0, 0, 0);
    __builtin_amdgcn_s_setprio(0);
}

__global__ __launch_bounds__(512, 2)
void gemm_8ph(const unsigned short* __restrict__ A,   // bf16 [TM][TK]
              const unsigned short* __restrict__ Bt,  // bf16 [TN][TK]
              const float* __restrict__ BIAS,         // fp32 [TN]
              float* __restrict__ OUT)                // fp32 [TM][TN]
{
    __shared__ __align__(16) short sh[2][2][BM2 * BK2];   // 128 KiB

    const int tid  = threadIdx.x;
    const int lane = tid & 63;
    const int wave = tid >> 6;          // 0..7
    const int wr   = wave >> 2;         // 0..1 (M half)
    const int wc   = wave & 3;          // 0..3 (N quarter)
    const int quad = lane >> 4;
    const int l16  = lane & 15;
    const int swz  = l16 & 7;

    // T1: bijective XCD chunk swizzle (688 = 8 * 86); bn fastest -> A reuse in L2
    const int bid  = blockIdx.x;
    const int wgid = (bid & 7) * (GRID2 / 8) + (bid >> 3);
    const int bm = wgid / NBN;
    const int bn = wgid % NBN;

    // staging: LDS dest linear (base + lane*16B); global source pre-swizzled
    const int srow = wave * 8 + (lane >> 3);            // 0..63
    const int scol = 8 * ((lane & 7) ^ (lane >> 3));    // elements
    const unsigned short* Ag = A  + (size_t)(bm * BM2 + srow) * TK + scol;
    const unsigned short* Bg = Bt + (size_t)(bn * BN2 + srow) * TK + scol;
    const int ldst = wave * 512 + lane * 8;             // shorts

    floatx4 acc[8][4];
    #pragma unroll
    for (int i = 0; i < 8; ++i)
        #pragma unroll
        for (int j = 0; j < 4; ++j)
            acc[i][j] = (floatx4){0.f, 0.f, 0.f, 0.f};

    short8 a03[4][2], a47[4][2], b01[2][2], b23[2][2];

    // prologue: K-tile 0 full -> buf0; K-tile 1 B-halves -> buf1
    STAGE(0, Ag, 0, 0, 0); STAGE(0, Ag, 0, 1, 0);
    STAGE(1, Bg, 0, 0, 0); STAGE(1, Bg, 0, 1, 0);
    STAGE(1, Bg, 1, 0, 1); STAGE(1, Bg, 1, 1, 1);
    VMW4;       // drain K-tile 0's 8 loads; 4 (t1 B) stay in flight
    BARRIER; SB0;
    RD_A4(a03, 0, 0); RD_B2(b01, 0, 0);   // frags for phase 1

    for (int it = 0; it < NKT / 2; ++it) {
        const int t  = 2 * it;
        const int t2 = (t + 2 < NKT) ? t + 2 : NKT - 1;   // tail stages: garbage,
        const int t3 = (t + 3 < NKT) ? t + 3 : NKT - 1;   // never consumed

        // ======== K-tile t (buf0) ========
        // p1: MFMA(a03,b01); prefetch b23; stage Ah0(t+1)->buf1
        STAGE(0, Ag, 1, 0, t + 1);
        RD_B2(b23, 0, 2);
        mfma_q<0, 0>(acc, a03, b01);
        BARRIER;

        // p2: MFMA(a03,b23); prefetch a47; stage Ah1(t+1)->buf1
        STAGE(0, Ag, 1, 1, t + 1);
        RD_A4(a47, 0, 4);
        mfma_q<0, 2>(acc, a03, b23);
        BARRIER;

        // p3: MFMA(a47,b01); stage Bh0(t+2)->buf0 (buf0-B reads consumed @p2)
        STAGE(1, Bg, 0, 0, t2);
        mfma_q<4, 0>(acc, a47, b01);
        BARRIER;

        // p4: stage Bh1(t+2)->buf0; drain (leaves p3,p4 = B(t+2) in flight);
        //     prefetch buf1 frags (a03,b01 of t+1); MFMA(a47,b23)
        STAGE(1, Bg, 0, 1, t2);
        VMW4;
        BARRIER; SB0;
        RD_A4(a03, 1, 0); RD_B2(b01, 1, 0);
        mfma_q<4, 2>(acc, a47, b23);
        BARRIER;

        // ======== K-tile t+1 (buf1) ========
        // p5: MFMA(a03,b01); prefetch b23(buf1); stage Ah0(t+2)->buf0
        STAGE(0, Ag, 0, 0, t2);
        RD_B2(b23, 1, 2);
        mfma_q<0, 0>(acc, a03, b01);
        BARRIER;

        // p6: MFMA(a03,b23); prefetch a47(buf1); stage Ah1(t+2)->buf0
        STAGE(0, Ag, 0, 1, t2);
        RD_A4(a47, 1, 4);
        mfma_q<0, 2>(acc, a03, b23);
        BARRIER;

        // p7: MFMA(a47,b01); stage Bh0(t+3)->buf1 (buf1-B reads consumed @p6)
        STAGE(1, Bg, 1, 0, t3);
        mfma_q<4, 0>(acc, a47, b01);
        BARRIER;

        // p8: stage Bh1(t+3)->buf1; drain (leaves p7,p8 = B(t+3) in flight);
        //     prefetch buf0 frags (t+2); MFMA(a47,b23)
        STAGE(1, Bg, 1, 1, t3);
        VMW4;
        BARRIER; SB0;
        RD_A4(a03, 0, 0); RD_B2(b01, 0, 0);
        mfma_q<4, 2>(acc, a47, b23);
        BARRIER;
    }

    // epilogue: C/D col=lane&15, row=quad*4+reg (dtype-independent layout)
    const int row0 = bm * BM2 + wr * 128 + quad * 4;
    const int col0 = bn * BN2 + wc * 64 + l16;
    #pragma unroll
    for (int ni = 0; ni < 4; ++ni) {
        const int col = col0 + ni * 16;
        const float bv = BIAS[col];
        #pragma unroll
        for (int mi = 0; mi < 8; ++mi) {
            #pragma unroll
            for (int r = 0; r < 4; ++r) {
                const int row = row0 + mi * 16 + r;
                OUT[(size_t)row * TN + col] = acc[mi][ni][r] + bv;
            }
        }
    }
}

// ---------------- Fallback: fused kernel (known-good, ws too small) ----------
__global__ __launch_bounds__(256)
void gemm_fused_fallback(const float* __restrict__ X, const int* __restrict__ QW,
                         const int* __restrict__ QZ, const float* __restrict__ SC,
                         const float* __restrict__ BIAS, float* __restrict__ OUT)
{
    __shared__ __align__(16) short As[BM * BK];
    __shared__ __align__(16) short Bs[BN * BK];

    const int tid  = threadIdx.x;
    const int lane = tid & 63;
    const int wave = tid >> 6;
    const int bm = blockIdx.x / (TN / BN);
    const int bn = blockIdx.x % (TN / BN);
    const int wm = (wave & 1) * 64;
    const int wn = (wave >> 1) * 64;
    const int quad = lane >> 4;
    const int l16  = lane & 15;

    const int a_r = tid >> 2;
    const int a_c = (tid & 3) * 8;
    const float* agp = X + (size_t)(bm * BM + a_r) * TK + a_c;
    short* alp = As + a_r * BK + a_c;

    const int b_n = tid & 127;
    const int b_p = tid >> 7;
    const int n_g = bn * BN + b_n;
    const int zsh = (n_g & 7) * 4;

    floatx4 acc[4][4];
    #pragma unroll
    for (int i = 0; i < 4; ++i)
        #pragma unroll
        for (int j = 0; j < 4; ++j)
            acc[i][j] = (floatx4){0.f, 0.f, 0.f, 0.f};

    for (int g = 0; g < NG; ++g) {
        const float s = SC[(size_t)g * TN + n_g];
        const int z = (int)(((unsigned)QZ[g * QZC + (n_g >> 3)] >> zsh) & 15u) + 1;
        const float zc = -s * (float)z;

        #pragma unroll
        for (int t = 0; t < GS / BK; ++t) {
            const int k0 = g * GS + t * BK;
            floatx4 v0 = *(const floatx4*)(agp + k0);
            floatx4 v1 = *(const floatx4*)(agp + k0 + 4);
            floatx4 v2 = *(const floatx4*)(agp + (size_t)64 * TK + k0);
            floatx4 v3 = *(const floatx4*)(agp + (size_t)64 * TK + k0 + 4);
            const unsigned q0 = (unsigned)QW[(size_t)(k0 / 8 + b_p)     * TN + n_g];
            const unsigned q1 = (unsigned)QW[(size_t)(k0 / 8 + b_p + 2) * TN + n_g];

            S8U aw0, aw1;
            aw0.u[0] = pack2(v0[0], v0[1]); aw0.u[1] = pack2(v0[2], v0[3]);
            aw0.u[2] = pack2(v1[0], v1[1]); aw0.u[3] = pack2(v1[2], v1[3]);
            aw1.u[0] = pack2(v2[0], v2[1]); aw1.u[1] = pack2(v2[2], v2[3]);
            aw1.u[2] = pack2(v3[0], v3[1]); aw1.u[3] = pack2(v3[2], v3[3]);
            *(short8*)alp = aw0.v;
            *(short8*)(alp + 64 * BK) = aw1.v;

            const unsigned qs[2] = {q0, q1};
            #pragma unroll
            for (int i = 0; i < 2; ++i) {
                const int p = b_p + i * 2;
                const unsigned q = qs[i];
                const unsigned qe = q & 0x0F0F0F0Fu;
                const unsigned qo = (q >> 4) & 0x0F0F0F0Fu;
                S8U vv;
                #pragma unroll
                for (int jj = 0; jj < 4; ++jj) {
                    const float w0 = (float)((qe >> (8 * jj)) & 0xFFu);
                    const float w1 = (float)((qo >> (8 * jj)) & 0xFFu);
                    vv.u[jj] = pack2(fmaf(w0, s, zc), fmaf(w1, s, zc));
                }
                *(short8*)(Bs + b_n * BK + p * 8) = vv.v;
            }

            __syncthreads();
            short8 af[4], bfr[4];
            #pragma unroll
            for (int i = 0; i < 4; ++i) {
                af[i]  = *(const short8*)(As + (wm + i * 16 + l16) * BK + quad * 8);
                bfr[i] = *(const short8*)(Bs + (wn + i * 16 + l16) * BK + quad * 8);
            }
            #pragma unroll
            for (int mi = 0; mi < 4; ++mi)
                #pragma unroll
                for (int ni = 0; ni < 4; ++ni)
                    acc[mi][ni] = __builtin_amdgcn_mfma_f32_16x16x32_bf16(
                        af[mi], bfr[ni], acc[mi][ni], 0, 0, 0);
            __syncthreads();
        }
    }

    const int col0 = bn * BN + wn + l16;
    const int row0 = bm * BM + wm + quad * 4;
    #pragma unroll
    for (int ni = 0; ni < 4; ++ni) {
        const int col = col0 + ni * 16;
        const float bv = BIAS[col];
        #pragma unroll
        for (int mi = 0; mi < 4; ++mi) {
            #pragma unroll
            for (int r = 0; r < 4; ++r) {
                const int row = row0 + mi * 16 + r;
                OUT[(size_t)row * TN + col] = acc[mi][ni][r] + bv;
            }
        }
    }
}

extern "C" void kernel_launch(void* const* d_in, const int* in_sizes, int n_in,
                              void* d_out, int out_size, void* d_ws, size_t ws_size,
                              hipStream_t stream) {
    // Resolve inputs by element count (all distinct); fall back to dict order.
    const void* px = nullptr; const void* pqw = nullptr; const void* pqz = nullptr;
    const void* psc = nullptr; const void* pbi = nullptr;
    for (int i = 0; i < n_in; ++i) {
        switch (in_sizes[i]) {
            case 16777216: px  = d_in[i]; break;  // x
            case 5636096:  pqw = d_in[i]; break;  // qweight
            case 352256:   psc = d_in[i]; break;  // scales
            case 44032:    pqz = d_in[i]; break;  // qzeros
            case 11008:    pbi = d_in[i]; break;  // bias
            default: break;                        // g_idx unused
        }
    }
    if (!px)  px  = d_in[0];
    if (!pqw) pqw = d_in[1];
    if (!pqz) pqz = d_in[2];
    if (!psc) psc = d_in[3];
    if (!pbi) pbi = d_in[5];

    if (ws_size >= WS_NEED) {
        unsigned short* Xb = (unsigned short*)d_ws;
        unsigned short* Wt = (unsigned short*)((char*)d_ws + XB_BYTES);

        prep<<<dim3(DQB + CVB), 256, 0, stream>>>(
            (const float*)px, Xb, (const int*)pqw, (const int*)pqz,
            (const float*)psc, Wt);
        gemm_8ph<<<dim3(GRID2), 512, 0, stream>>>(
            Xb, Wt, (const float*)pbi, (float*)d_out);
    } else {
        gemm_fused_fallback<<<dim3((TM / BM) * (TN / BN)), 256, 0, stream>>>(
            (const float*)px, (const int*)pqw, (const int*)pqz,
            (const float*)psc, (const float*)pbi, (float*)d_out);
    }
}

// Round 4
// 578.989 us; speedup vs baseline: 1.7255x; 1.7255x over previous
//
#include <hip/hip_runtime.h>

// GPTQ 4-bit quantized linear, MI355X (gfx950). fp32 in/out.
// out[M,N] = x[M,K] @ dequant(qweight)[K,N] + bias[N]
// M=4096, K=4096, N=11008, groupsize=128.
//
// Round 9:
//  - gemm_8ph reverted byte-for-byte to round 6 (359 us, MfmaUtil 46.7).
//    Round 7/8's phase-ahead prefetch kept 96 frag VGPRs live -> scratch
//    spills (FETCH +212MB / WRITE +68MB) -> 2.2x regression. Register
//    budget, not barrier count, is the binding constraint at this tile.
//  - dequant_w rewritten: coalesced QW reads (lane-consecutive n; each
//    thread owns one column's 16-pack k-group) + LDS transpose (272 B row
//    stride) + the original verified 256B-per-16-lane store pattern.
//    Old version read 4 B at 44 KB lane stride (up to 16x amplification).

#define TM 4096
#define TK 4096
#define TN 11008
#define GS 128
#define NG (TK / GS)
#define QZC (TN / 8)

// ---- phase-2 geometry (256x256 tile, BK=64, 8 waves / 512 threads) ----
#define BM2 256
#define BN2 256
#define BK2 64
#define NKT (TK / BK2)                    // 64 K-tiles
#define NBN (TN / BN2)                    // 43
#define GRID2 ((TM / BM2) * (TN / BN2))   // 16*43 = 688 (== 0 mod 8)

// ---- dequant geometry ----
#define DQN 256                           // n-columns per block
#define DQROW 136                         // LDS row stride in shorts (272 B)

// ---- legacy 128^2 geometry (fallback kernel) ----
#define BM 128
#define BN 128
#define BK 32

#define XB_BYTES ((size_t)TM * TK * 2)            // 33,554,432
#define WT_BYTES ((size_t)TN * TK * 2)            // 90,177,536
#define WS_NEED  (XB_BYTES + WT_BYTES)

typedef __attribute__((ext_vector_type(8))) short short8;
typedef __attribute__((ext_vector_type(4))) float floatx4;

union S8U { short8 v; unsigned u[4]; };

__device__ __forceinline__ unsigned short f2bf_rn(float f) {
    unsigned u = __builtin_bit_cast(unsigned, f);
    u += 0x7FFFu + ((u >> 16) & 1u);
    return (unsigned short)(u >> 16);
}
__device__ __forceinline__ unsigned pack2(float a, float b) {
    return (unsigned)f2bf_rn(a) | ((unsigned)f2bf_rn(b) << 16);
}

// ---------------- Phase 1a: X fp32 -> bf16 ----------------
__global__ __launch_bounds__(256)
void conv_x(const float* __restrict__ X, unsigned short* __restrict__ Xb)
{
    const size_t i = ((size_t)blockIdx.x * 256 + threadIdx.x) * 8;  // 8 floats/thread
    floatx4 v0 = *(const floatx4*)(X + i);
    floatx4 v1 = *(const floatx4*)(X + i + 4);
    S8U o;
    o.u[0] = pack2(v0[0], v0[1]); o.u[1] = pack2(v0[2], v0[3]);
    o.u[2] = pack2(v1[0], v1[1]); o.u[3] = pack2(v1[2], v1[3]);
    *(short8*)(Xb + i) = o.v;
}

// ---------------- Phase 1b: dequant qweight -> bf16 W^T[N][K] ----------------
// Block: 1 group (16 packs = 128 k) x 256 n-columns. 256 threads.
// Read phase: thread t owns column n = n0+t -> QW reads lane-consecutive in n
// (fully coalesced, 1 KB per instruction across the block). The int32 packs
// are k-major, so thread t accumulates row n's whole 256 B group-chunk and
// parks it in LDS. Write phase: original verified pattern -- 16 lanes cover
// one row's 256 B chunk contiguously.
__global__ __launch_bounds__(256)
void dequant_w(const int* __restrict__ QW, const int* __restrict__ QZ,
               const float* __restrict__ SC, unsigned short* __restrict__ Wt)
{
    __shared__ __align__(16) short lds[DQN * DQROW];   // 69,632 B

    const int g  = blockIdx.x % NG;           // k-group
    const int n0 = (blockIdx.x / NG) * DQN;   // n-tile base
    const int t  = threadIdx.x;
    const int n  = n0 + t;

    const float s = SC[(size_t)g * TN + n];
    const int z = (int)(((unsigned)QZ[g * QZC + (n >> 3)] >> ((n & 7) * 4)) & 15u) + 1;
    const float zc = -s * (float)z;

    #pragma unroll
    for (int i = 0; i < 16; ++i) {
        const unsigned q = (unsigned)QW[(size_t)(g * 16 + i) * TN + n];  // coalesced
        const unsigned qe = q & 0x0F0F0F0Fu;          // nibbles 0,2,4,6
        const unsigned qo = (q >> 4) & 0x0F0F0F0Fu;   // nibbles 1,3,5,7
        S8U vv;
        #pragma unroll
        for (int jj = 0; jj < 4; ++jj) {
            const float w0 = (float)((qe >> (8 * jj)) & 0xFFu);
            const float w1 = (float)((qo >> (8 * jj)) & 0xFFu);
            vv.u[jj] = pack2(fmaf(w0, s, zc), fmaf(w1, s, zc));
        }
        *(short8*)(lds + t * DQROW + i * 8) = vv.v;
    }
    __syncthreads();

    const int c  = t & 15;          // pack chunk within group
    const int r0 = t >> 4;          // row base
    #pragma unroll
    for (int j = 0; j < 16; ++j) {
        const int nl = r0 + 16 * j;
        const short8 v = *(const short8*)(lds + nl * DQROW + c * 8);
        *(short8*)(Wt + (size_t)(n0 + nl) * TK + g * 128 + c * 8) = v;
    }
}

// ---------------- Phase 2: 256^2 8-phase bf16 GEMM (round-6 verified) -------
#define GLDS(gp, lp) __builtin_amdgcn_global_load_lds( \
    (const __attribute__((address_space(1))) void*)(gp), \
    (__attribute__((address_space(3))) void*)(lp), 16, 0, 0)

// op: 0=A, 1=B. half: 0 = rows [0,128), 1 = rows [128,256).
#define STAGE(op, gptr, buf, half, kt) do {                                   \
    const unsigned short* _g = (gptr) + (size_t)(half) * 128 * TK             \
                                      + (size_t)(kt) * BK2;                   \
    short* _l = &sh[buf][op][(half) * 8192 + ldst];                           \
    GLDS(_g, _l);                                                             \
    GLDS(_g + (size_t)64 * TK, _l + 4096);                                    \
} while (0)

// swizzled fragment reads: global 16B-chunk c sits at LDS slot c ^ (row&7)
#define RDA(buf, mi, ks) (*(const short8*)&sh[buf][0][ \
    (wr * 128 + (mi) * 16 + l16) * 64 + ((((ks) << 2) | quad) ^ swz) * 8])
#define RDB(buf, ni, ks) (*(const short8*)&sh[buf][1][ \
    (wc * 64 + (ni) * 16 + l16) * 64 + ((((ks) << 2) | quad) ^ swz) * 8])

#define BARRIER __builtin_amdgcn_s_barrier()
#define LGKM0 do { asm volatile("s_waitcnt lgkmcnt(0)" ::: "memory");         \
                   __builtin_amdgcn_sched_barrier(0); } while (0)
#define VMW4  asm volatile("s_waitcnt vmcnt(4)" ::: "memory")

template<int MI0, int NI0>
__device__ __forceinline__ void mfma_quad(floatx4 (&acc)[8][4],
                                          const short8 (&a)[4][2],
                                          const short8 (&b)[4][2]) {
    __builtin_amdgcn_s_setprio(1);
    #pragma unroll
    for (int m = 0; m < 4; ++m)
        #pragma unroll
        for (int n = 0; n < 2; ++n)
            #pragma unroll
            for (int ks = 0; ks < 2; ++ks)
                acc[MI0 + m][NI0 + n] = __builtin_amdgcn_mfma_f32_16x16x32_bf16(
                    a[m][ks], b[NI0 + n][ks], acc[MI0 + m][NI0 + n], 0, 0, 0);
    __builtin_amdgcn_s_setprio(0);
}

__global__ __launch_bounds__(512, 2)
void gemm_8ph(const unsigned short* __restrict__ A,   // bf16 [TM][TK]
              const unsigned short* __restrict__ Bt,  // bf16 [TN][TK]
              const float* __restrict__ BIAS,         // fp32 [TN]
              float* __restrict__ OUT)                // fp32 [TM][TN]
{
    __shared__ __align__(16) short sh[2][2][BM2 * BK2];   // 128 KiB

    const int tid  = threadIdx.x;
    const int lane = tid & 63;
    const int wave = tid >> 6;          // 0..7
    const int wr   = wave >> 2;         // 0..1 (M half)
    const int wc   = wave & 3;          // 0..3 (N quarter)
    const int quad = lane >> 4;
    const int l16  = lane & 15;
    const int swz  = l16 & 7;

    // T1: bijective XCD chunk swizzle (688 = 8 * 86); bn fastest -> A reuse in L2
    const int bid  = blockIdx.x;
    const int wgid = (bid & 7) * (GRID2 / 8) + (bid >> 3);
    const int bm = wgid / NBN;
    const int bn = wgid % NBN;

    // staging: LDS dest linear (base + lane*16B); global source pre-swizzled
    const int srow = wave * 8 + (lane >> 3);            // 0..63
    const int scol = 8 * ((lane & 7) ^ (lane >> 3));    // elements
    const unsigned short* Ag = A  + (size_t)(bm * BM2 + srow) * TK + scol;
    const unsigned short* Bg = Bt + (size_t)(bn * BN2 + srow) * TK + scol;
    const int ldst = wave * 512 + lane * 8;             // shorts

    floatx4 acc[8][4];
    #pragma unroll
    for (int i = 0; i < 8; ++i)
        #pragma unroll
        for (int j = 0; j < 4; ++j)
            acc[i][j] = (floatx4){0.f, 0.f, 0.f, 0.f};

    short8 a[4][2], b[4][2];

    // prologue: K-tile 0 full -> buf0; K-tile 1 B-halves -> buf1
    STAGE(0, Ag, 0, 0, 0); STAGE(0, Ag, 0, 1, 0);
    STAGE(1, Bg, 0, 0, 0); STAGE(1, Bg, 0, 1, 0);
    STAGE(1, Bg, 1, 0, 1); STAGE(1, Bg, 1, 1, 1);
    VMW4;       // drain K-tile 0's 8 loads; 4 (t1 B) stay in flight
    BARRIER;

    for (int it = 0; it < NKT / 2; ++it) {
        const int t  = 2 * it;
        const int t2 = (t + 2 < NKT) ? t + 2 : NKT - 1;   // tail stages: garbage,
        const int t3 = (t + 3 < NKT) ? t + 3 : NKT - 1;   // never consumed

        // ======== K-tile t (buf0) ========
        // p1: q(mi 0-3, ni 0-1); stage Ah0(t+1)->buf1
        #pragma unroll
        for (int m = 0; m < 4; ++m) { a[m][0] = RDA(0, m, 0); a[m][1] = RDA(0, m, 1); }
        #pragma unroll
        for (int n = 0; n < 2; ++n) { b[n][0] = RDB(0, n, 0); b[n][1] = RDB(0, n, 1); }
        STAGE(0, Ag, 1, 0, t + 1);
        BARRIER; LGKM0;
        mfma_quad<0, 0>(acc, a, b);
        BARRIER;

        // p2: q(0-3, 2-3); stage Ah1(t+1)->buf1
        #pragma unroll
        for (int n = 2; n < 4; ++n) { b[n][0] = RDB(0, n, 0); b[n][1] = RDB(0, n, 1); }
        STAGE(0, Ag, 1, 1, t + 1);
        BARRIER; LGKM0;
        mfma_quad<0, 2>(acc, a, b);
        BARRIER;

        // p3: q(4-7, 0-1); stage Bh0(t+2)->buf0 (buf0-B reads done @p2)
        #pragma unroll
        for (int m = 0; m < 4; ++m) { a[m][0] = RDA(0, m + 4, 0); a[m][1] = RDA(0, m + 4, 1); }
        STAGE(1, Bg, 0, 0, t2);
        BARRIER; LGKM0;
        mfma_quad<4, 0>(acc, a, b);
        BARRIER;

        // p4: q(4-7, 2-3); stage Bh1(t+2)->buf0; counted wait:
        // 4 newest = p3/p4 stages; drains Ah(t+1) + Bh(t+1) before p5 reads buf1
        STAGE(1, Bg, 0, 1, t2);
        VMW4;
        BARRIER;
        mfma_quad<4, 2>(acc, a, b);
        BARRIER;

        // ======== K-tile t+1 (buf1) ========
        // p5: q(0-3, 0-1); stage Ah0(t+2)->buf0 (buf0-A reads done @p3)
        #pragma unroll
        for (int m = 0; m < 4; ++m) { a[m][0] = RDA(1, m, 0); a[m][1] = RDA(1, m, 1); }
        #pragma unroll
        for (int n = 0; n < 2; ++n) { b[n][0] = RDB(1, n, 0); b[n][1] = RDB(1, n, 1); }
        STAGE(0, Ag, 0, 0, t2);
        BARRIER; LGKM0;
        mfma_quad<0, 0>(acc, a, b);
        BARRIER;

        // p6: q(0-3, 2-3); stage Ah1(t+2)->buf0
        #pragma unroll
        for (int n = 2; n < 4; ++n) { b[n][0] = RDB(1, n, 0); b[n][1] = RDB(1, n, 1); }
        STAGE(0, Ag, 0, 1, t2);
        BARRIER; LGKM0;
        mfma_quad<0, 2>(acc, a, b);
        BARRIER;

        // p7: q(4-7, 0-1); stage Bh0(t+3)->buf1 (buf1-B reads done @p6)
        #pragma unroll
        for (int m = 0; m < 4; ++m) { a[m][0] = RDA(1, m + 4, 0); a[m][1] = RDA(1, m + 4, 1); }
        STAGE(1, Bg, 1, 0, t3);
        BARRIER; LGKM0;
        mfma_quad<4, 0>(acc, a, b);
        BARRIER;

        // p8: q(4-7, 2-3); stage Bh1(t+3)->buf1; counted wait:
        // 4 newest = p7/p8 stages; drains Bh(t+2)+Ah(t+2) before next-iter p1
        STAGE(1, Bg, 1, 1, t3);
        VMW4;
        BARRIER;
        mfma_quad<4, 2>(acc, a, b);
        BARRIER;
    }

    // epilogue: C/D col=lane&15, row=quad*4+reg (dtype-independent layout)
    const int row0 = bm * BM2 + wr * 128 + quad * 4;
    const int col0 = bn * BN2 + wc * 64 + l16;
    #pragma unroll
    for (int ni = 0; ni < 4; ++ni) {
        const int col = col0 + ni * 16;
        const float bv = BIAS[col];
        #pragma unroll
        for (int mi = 0; mi < 8; ++mi) {
            #pragma unroll
            for (int r = 0; r < 4; ++r) {
                const int row = row0 + mi * 16 + r;
                OUT[(size_t)row * TN + col] = acc[mi][ni][r] + bv;
            }
        }
    }
}

// ---------------- Fallback: fused kernel (known-good, ws too small) ----------
__global__ __launch_bounds__(256)
void gemm_fused_fallback(const float* __restrict__ X, const int* __restrict__ QW,
                         const int* __restrict__ QZ, const float* __restrict__ SC,
                         const float* __restrict__ BIAS, float* __restrict__ OUT)
{
    __shared__ __align__(16) short As[BM * BK];
    __shared__ __align__(16) short Bs[BN * BK];

    const int tid  = threadIdx.x;
    const int lane = tid & 63;
    const int wave = tid >> 6;
    const int bm = blockIdx.x / (TN / BN);
    const int bn = blockIdx.x % (TN / BN);
    const int wm = (wave & 1) * 64;
    const int wn = (wave >> 1) * 64;
    const int quad = lane >> 4;
    const int l16  = lane & 15;

    const int a_r = tid >> 2;
    const int a_c = (tid & 3) * 8;
    const float* agp = X + (size_t)(bm * BM + a_r) * TK + a_c;
    short* alp = As + a_r * BK + a_c;

    const int b_n = tid & 127;
    const int b_p = tid >> 7;
    const int n_g = bn * BN + b_n;
    const int zsh = (n_g & 7) * 4;

    floatx4 acc[4][4];
    #pragma unroll
    for (int i = 0; i < 4; ++i)
        #pragma unroll
        for (int j = 0; j < 4; ++j)
            acc[i][j] = (floatx4){0.f, 0.f, 0.f, 0.f};

    for (int g = 0; g < NG; ++g) {
        const float s = SC[(size_t)g * TN + n_g];
        const int z = (int)(((unsigned)QZ[g * QZC + (n_g >> 3)] >> zsh) & 15u) + 1;
        const float zc = -s * (float)z;

        #pragma unroll
        for (int t = 0; t < GS / BK; ++t) {
            const int k0 = g * GS + t * BK;
            floatx4 v0 = *(const floatx4*)(agp + k0);
            floatx4 v1 = *(const floatx4*)(agp + k0 + 4);
            floatx4 v2 = *(const floatx4*)(agp + (size_t)64 * TK + k0);
            floatx4 v3 = *(const floatx4*)(agp + (size_t)64 * TK + k0 + 4);
            const unsigned q0 = (unsigned)QW[(size_t)(k0 / 8 + b_p)     * TN + n_g];
            const unsigned q1 = (unsigned)QW[(size_t)(k0 / 8 + b_p + 2) * TN + n_g];

            S8U aw0, aw1;
            aw0.u[0] = pack2(v0[0], v0[1]); aw0.u[1] = pack2(v0[2], v0[3]);
            aw0.u[2] = pack2(v1[0], v1[1]); aw0.u[3] = pack2(v1[2], v1[3]);
            aw1.u[0] = pack2(v2[0], v2[1]); aw1.u[1] = pack2(v2[2], v2[3]);
            aw1.u[2] = pack2(v3[0], v3[1]); aw1.u[3] = pack2(v3[2], v3[3]);
            *(short8*)alp = aw0.v;
            *(short8*)(alp + 64 * BK) = aw1.v;

            const unsigned qs[2] = {q0, q1};
            #pragma unroll
            for (int i = 0; i < 2; ++i) {
                const int p = b_p + i * 2;
                const unsigned q = qs[i];
                const unsigned qe = q & 0x0F0F0F0Fu;
                const unsigned qo = (q >> 4) & 0x0F0F0F0Fu;
                S8U vv;
                #pragma unroll
                for (int jj = 0; jj < 4; ++jj) {
                    const float w0 = (float)((qe >> (8 * jj)) & 0xFFu);
                    const float w1 = (float)((qo >> (8 * jj)) & 0xFFu);
                    vv.u[jj] = pack2(fmaf(w0, s, zc), fmaf(w1, s, zc));
                }
                *(short8*)(Bs + b_n * BK + p * 8) = vv.v;
            }

            __syncthreads();
            short8 af[4], bfr[4];
            #pragma unroll
            for (int i = 0; i < 4; ++i) {
                af[i]  = *(const short8*)(As + (wm + i * 16 + l16) * BK + quad * 8);
                bfr[i] = *(const short8*)(Bs + (wn + i * 16 + l16) * BK + quad * 8);
            }
            #pragma unroll
            for (int mi = 0; mi < 4; ++mi)
                #pragma unroll
                for (int ni = 0; ni < 4; ++ni)
                    acc[mi][ni] = __builtin_amdgcn_mfma_f32_16x16x32_bf16(
                        af[mi], bfr[ni], acc[mi][ni], 0, 0, 0);
            __syncthreads();
        }
    }

    const int col0 = bn * BN + wn + l16;
    const int row0 = bm * BM + wm + quad * 4;
    #pragma unroll
    for (int ni = 0; ni < 4; ++ni) {
        const int col = col0 + ni * 16;
        const float bv = BIAS[col];
        #pragma unroll
        for (int mi = 0; mi < 4; ++mi) {
            #pragma unroll
            for (int r = 0; r < 4; ++r) {
                const int row = row0 + mi * 16 + r;
                OUT[(size_t)row * TN + col] = acc[mi][ni][r] + bv;
            }
        }
    }
}

extern "C" void kernel_launch(void* const* d_in, const int* in_sizes, int n_in,
                              void* d_out, int out_size, void* d_ws, size_t ws_size,
                              hipStream_t stream) {
    // Resolve inputs by element count (all distinct); fall back to dict order.
    const void* px = nullptr; const void* pqw = nullptr; const void* pqz = nullptr;
    const void* psc = nullptr; const void* pbi = nullptr;
    for (int i = 0; i < n_in; ++i) {
        switch (in_sizes[i]) {
            case 16777216: px  = d_in[i]; break;  // x
            case 5636096:  pqw = d_in[i]; break;  // qweight
            case 352256:   psc = d_in[i]; break;  // scales
            case 44032:    pqz = d_in[i]; break;  // qzeros
            case 11008:    pbi = d_in[i]; break;  // bias
            default: break;                        // g_idx unused
        }
    }
    if (!px)  px  = d_in[0];
    if (!pqw) pqw = d_in[1];
    if (!pqz) pqz = d_in[2];
    if (!psc) psc = d_in[3];
    if (!pbi) pbi = d_in[5];

    if (ws_size >= WS_NEED) {
        unsigned short* Xb = (unsigned short*)d_ws;
        unsigned short* Wt = (unsigned short*)((char*)d_ws + XB_BYTES);

        conv_x<<<dim3(TM * TK / 8 / 256), 256, 0, stream>>>((const float*)px, Xb);
        dequant_w<<<dim3(NG * (TN / DQN)), 256, 0, stream>>>(
            (const int*)pqw, (const int*)pqz, (const float*)psc, Wt);
        gemm_8ph<<<dim3(GRID2), 512, 0, stream>>>(
            Xb, Wt, (const float*)pbi, (float*)d_out);
    } else {
        gemm_fused_fallback<<<dim3((TM / BM) * (TN / BN)), 256, 0, stream>>>(
            (const float*)px, (const int*)pqw, (const int*)pqz,
            (const float*)psc, (const float*)pbi, (float*)d_out);
    }
}

// Round 5
// 556.707 us; speedup vs baseline: 1.7945x; 1.0400x over previous
//
#include <hip/hip_runtime.h>

// GPTQ 4-bit quantized linear, MI355X (gfx950). fp32 in/out.
// out[M,N] = x[M,K] @ dequant(qweight)[K,N] + bias[N]
// M=4096, K=4096, N=11008, groupsize=128.
//
// Round 10: gemm_8ph barrier reduction, 16 -> 8 barriers/iter.
//  Race proof: the only cross-wave ordering needed is "all waves' ds_reads of
//  region R complete before any wave's STAGE writes R". Wave V's reads(phase j)
//  drain at V's own lgkmcnt(0) BEFORE V's MFMA(j), which precedes V reaching
//  the end-of-phase-j barrier; any wave's STAGE that targets R sits in a later
//  inter-barrier window -> safe without the pre-MFMA barrier. Within-window
//  STAGE vs read regions verified disjoint for all 8 phases (A-half vs B-half,
//  or other buffer). VMW4 mid-phase barriers (p4/p8) kept -- they publish the
//  per-wave vmcnt drain to the block. Read placement IDENTICAL to round 6
//  (live frag set 64 VGPR -- round 7's spill trap was phase-ahead reads, not
//  barrier count). Prep kernels untouched (round-9 finding: e2e gap is fixed
//  harness overhead, insensitive to prep implementation).

#define TM 4096
#define TK 4096
#define TN 11008
#define GS 128
#define NG (TK / GS)
#define QZC (TN / 8)

// ---- phase-2 geometry (256x256 tile, BK=64, 8 waves / 512 threads) ----
#define BM2 256
#define BN2 256
#define BK2 64
#define NKT (TK / BK2)                    // 64 K-tiles
#define NBN (TN / BN2)                    // 43
#define GRID2 ((TM / BM2) * (TN / BN2))   // 16*43 = 688 (== 0 mod 8)

// ---- dequant geometry ----
#define DQN 256                           // n-columns per block
#define DQROW 136                         // LDS row stride in shorts (272 B)

// ---- legacy 128^2 geometry (fallback kernel) ----
#define BM 128
#define BN 128
#define BK 32

#define XB_BYTES ((size_t)TM * TK * 2)            // 33,554,432
#define WT_BYTES ((size_t)TN * TK * 2)            // 90,177,536
#define WS_NEED  (XB_BYTES + WT_BYTES)

typedef __attribute__((ext_vector_type(8))) short short8;
typedef __attribute__((ext_vector_type(4))) float floatx4;

union S8U { short8 v; unsigned u[4]; };

__device__ __forceinline__ unsigned short f2bf_rn(float f) {
    unsigned u = __builtin_bit_cast(unsigned, f);
    u += 0x7FFFu + ((u >> 16) & 1u);
    return (unsigned short)(u >> 16);
}
__device__ __forceinline__ unsigned pack2(float a, float b) {
    return (unsigned)f2bf_rn(a) | ((unsigned)f2bf_rn(b) << 16);
}

// ---------------- Phase 1a: X fp32 -> bf16 ----------------
__global__ __launch_bounds__(256)
void conv_x(const float* __restrict__ X, unsigned short* __restrict__ Xb)
{
    const size_t i = ((size_t)blockIdx.x * 256 + threadIdx.x) * 8;  // 8 floats/thread
    floatx4 v0 = *(const floatx4*)(X + i);
    floatx4 v1 = *(const floatx4*)(X + i + 4);
    S8U o;
    o.u[0] = pack2(v0[0], v0[1]); o.u[1] = pack2(v0[2], v0[3]);
    o.u[2] = pack2(v1[0], v1[1]); o.u[3] = pack2(v1[2], v1[3]);
    *(short8*)(Xb + i) = o.v;
}

// ---------------- Phase 1b: dequant qweight -> bf16 W^T[N][K] ----------------
// Coalesced QW reads (lane-consecutive n) + LDS transpose (272 B row stride)
// + 256B-per-16-lane output store pattern. (round-9 verified)
__global__ __launch_bounds__(256)
void dequant_w(const int* __restrict__ QW, const int* __restrict__ QZ,
               const float* __restrict__ SC, unsigned short* __restrict__ Wt)
{
    __shared__ __align__(16) short lds[DQN * DQROW];   // 69,632 B

    const int g  = blockIdx.x % NG;           // k-group
    const int n0 = (blockIdx.x / NG) * DQN;   // n-tile base
    const int t  = threadIdx.x;
    const int n  = n0 + t;

    const float s = SC[(size_t)g * TN + n];
    const int z = (int)(((unsigned)QZ[g * QZC + (n >> 3)] >> ((n & 7) * 4)) & 15u) + 1;
    const float zc = -s * (float)z;

    #pragma unroll
    for (int i = 0; i < 16; ++i) {
        const unsigned q = (unsigned)QW[(size_t)(g * 16 + i) * TN + n];  // coalesced
        const unsigned qe = q & 0x0F0F0F0Fu;          // nibbles 0,2,4,6
        const unsigned qo = (q >> 4) & 0x0F0F0F0Fu;   // nibbles 1,3,5,7
        S8U vv;
        #pragma unroll
        for (int jj = 0; jj < 4; ++jj) {
            const float w0 = (float)((qe >> (8 * jj)) & 0xFFu);
            const float w1 = (float)((qo >> (8 * jj)) & 0xFFu);
            vv.u[jj] = pack2(fmaf(w0, s, zc), fmaf(w1, s, zc));
        }
        *(short8*)(lds + t * DQROW + i * 8) = vv.v;
    }
    __syncthreads();

    const int c  = t & 15;          // pack chunk within group
    const int r0 = t >> 4;          // row base
    #pragma unroll
    for (int j = 0; j < 16; ++j) {
        const int nl = r0 + 16 * j;
        const short8 v = *(const short8*)(lds + nl * DQROW + c * 8);
        *(short8*)(Wt + (size_t)(n0 + nl) * TK + g * 128 + c * 8) = v;
    }
}

// ---------------- Phase 2: 256^2 8-phase bf16 GEMM ----------------
#define GLDS(gp, lp) __builtin_amdgcn_global_load_lds( \
    (const __attribute__((address_space(1))) void*)(gp), \
    (__attribute__((address_space(3))) void*)(lp), 16, 0, 0)

// op: 0=A, 1=B. half: 0 = rows [0,128), 1 = rows [128,256).
#define STAGE(op, gptr, buf, half, kt) do {                                   \
    const unsigned short* _g = (gptr) + (size_t)(half) * 128 * TK             \
                                      + (size_t)(kt) * BK2;                   \
    short* _l = &sh[buf][op][(half) * 8192 + ldst];                           \
    GLDS(_g, _l);                                                             \
    GLDS(_g + (size_t)64 * TK, _l + 4096);                                    \
} while (0)

// swizzled fragment reads: global 16B-chunk c sits at LDS slot c ^ (row&7)
#define RDA(buf, mi, ks) (*(const short8*)&sh[buf][0][ \
    (wr * 128 + (mi) * 16 + l16) * 64 + ((((ks) << 2) | quad) ^ swz) * 8])
#define RDB(buf, ni, ks) (*(const short8*)&sh[buf][1][ \
    (wc * 64 + (ni) * 16 + l16) * 64 + ((((ks) << 2) | quad) ^ swz) * 8])

#define BARRIER __builtin_amdgcn_s_barrier()
#define LGKM0 do { asm volatile("s_waitcnt lgkmcnt(0)" ::: "memory");         \
                   __builtin_amdgcn_sched_barrier(0); } while (0)
#define VMW4  asm volatile("s_waitcnt vmcnt(4)" ::: "memory")

template<int MI0, int NI0>
__device__ __forceinline__ void mfma_quad(floatx4 (&acc)[8][4],
                                          const short8 (&a)[4][2],
                                          const short8 (&b)[4][2]) {
    __builtin_amdgcn_s_setprio(1);
    #pragma unroll
    for (int m = 0; m < 4; ++m)
        #pragma unroll
        for (int n = 0; n < 2; ++n)
            #pragma unroll
            for (int ks = 0; ks < 2; ++ks)
                acc[MI0 + m][NI0 + n] = __builtin_amdgcn_mfma_f32_16x16x32_bf16(
                    a[m][ks], b[NI0 + n][ks], acc[MI0 + m][NI0 + n], 0, 0, 0);
    __builtin_amdgcn_s_setprio(0);
}

__global__ __launch_bounds__(512, 2)
void gemm_8ph(const unsigned short* __restrict__ A,   // bf16 [TM][TK]
              const unsigned short* __restrict__ Bt,  // bf16 [TN][TK]
              const float* __restrict__ BIAS,         // fp32 [TN]
              float* __restrict__ OUT)                // fp32 [TM][TN]
{
    __shared__ __align__(16) short sh[2][2][BM2 * BK2];   // 128 KiB

    const int tid  = threadIdx.x;
    const int lane = tid & 63;
    const int wave = tid >> 6;          // 0..7
    const int wr   = wave >> 2;         // 0..1 (M half)
    const int wc   = wave & 3;          // 0..3 (N quarter)
    const int quad = lane >> 4;
    const int l16  = lane & 15;
    const int swz  = l16 & 7;

    // T1: bijective XCD chunk swizzle (688 = 8 * 86); bn fastest -> A reuse in L2
    const int bid  = blockIdx.x;
    const int wgid = (bid & 7) * (GRID2 / 8) + (bid >> 3);
    const int bm = wgid / NBN;
    const int bn = wgid % NBN;

    // staging: LDS dest linear (base + lane*16B); global source pre-swizzled
    const int srow = wave * 8 + (lane >> 3);            // 0..63
    const int scol = 8 * ((lane & 7) ^ (lane >> 3));    // elements
    const unsigned short* Ag = A  + (size_t)(bm * BM2 + srow) * TK + scol;
    const unsigned short* Bg = Bt + (size_t)(bn * BN2 + srow) * TK + scol;
    const int ldst = wave * 512 + lane * 8;             // shorts

    floatx4 acc[8][4];
    #pragma unroll
    for (int i = 0; i < 8; ++i)
        #pragma unroll
        for (int j = 0; j < 4; ++j)
            acc[i][j] = (floatx4){0.f, 0.f, 0.f, 0.f};

    short8 a[4][2], b[4][2];

    // prologue: K-tile 0 full -> buf0; K-tile 1 B-halves -> buf1
    STAGE(0, Ag, 0, 0, 0); STAGE(0, Ag, 0, 1, 0);
    STAGE(1, Bg, 0, 0, 0); STAGE(1, Bg, 0, 1, 0);
    STAGE(1, Bg, 1, 0, 1); STAGE(1, Bg, 1, 1, 1);
    VMW4;       // drain K-tile 0's 8 loads; 4 (t1 B) stay in flight
    BARRIER;

    for (int it = 0; it < NKT / 2; ++it) {
        const int t  = 2 * it;
        const int t2 = (t + 2 < NKT) ? t + 2 : NKT - 1;   // tail stages: garbage,
        const int t3 = (t + 3 < NKT) ? t + 3 : NKT - 1;   // never consumed

        // ======== K-tile t (buf0) ========
        // p1: reads buf0 a03+b01; stage Ah0(t+1)->buf1 (disjoint from reads);
        //     per-wave lgkmcnt gate -> MFMA; single end barrier
        #pragma unroll
        for (int m = 0; m < 4; ++m) { a[m][0] = RDA(0, m, 0); a[m][1] = RDA(0, m, 1); }
        #pragma unroll
        for (int n = 0; n < 2; ++n) { b[n][0] = RDB(0, n, 0); b[n][1] = RDB(0, n, 1); }
        STAGE(0, Ag, 1, 0, t + 1);
        LGKM0;
        mfma_quad<0, 0>(acc, a, b);
        BARRIER;

        // p2: reads buf0 b23; stage Ah1(t+1)->buf1
        #pragma unroll
        for (int n = 2; n < 4; ++n) { b[n][0] = RDB(0, n, 0); b[n][1] = RDB(0, n, 1); }
        STAGE(0, Ag, 1, 1, t + 1);
        LGKM0;
        mfma_quad<0, 2>(acc, a, b);
        BARRIER;

        // p3: reads buf0 a47 (A-half); stage Bh0(t+2)->buf0 B-half (disjoint;
        //     buf0-B reads completed at every wave's p2 LGKM0, published by p2's
        //     end barrier)
        #pragma unroll
        for (int m = 0; m < 4; ++m) { a[m][0] = RDA(0, m + 4, 0); a[m][1] = RDA(0, m + 4, 1); }
        STAGE(1, Bg, 0, 0, t2);
        LGKM0;
        mfma_quad<4, 0>(acc, a, b);
        BARRIER;

        // p4: stage Bh1(t+2)->buf0; counted drain (leaves p3/p4 B(t+2) loads in
        //     flight) + mid barrier publishes it block-wide; MFMA after barrier
        STAGE(1, Bg, 0, 1, t2);
        VMW4;
        BARRIER;
        mfma_quad<4, 2>(acc, a, b);

        // ======== K-tile t+1 (buf1) ========
        // p5: reads buf1 a03+b01 (drained by p4's VMW4+barrier); stage
        //     Ah0(t+2)->buf0 (buf0-A reads done at p3's LGKM0)
        #pragma unroll
        for (int m = 0; m < 4; ++m) { a[m][0] = RDA(1, m, 0); a[m][1] = RDA(1, m, 1); }
        #pragma unroll
        for (int n = 0; n < 2; ++n) { b[n][0] = RDB(1, n, 0); b[n][1] = RDB(1, n, 1); }
        STAGE(0, Ag, 0, 0, t2);
        LGKM0;
        mfma_quad<0, 0>(acc, a, b);
        BARRIER;

        // p6: reads buf1 b23; stage Ah1(t+2)->buf0
        #pragma unroll
        for (int n = 2; n < 4; ++n) { b[n][0] = RDB(1, n, 0); b[n][1] = RDB(1, n, 1); }
        STAGE(0, Ag, 0, 1, t2);
        LGKM0;
        mfma_quad<0, 2>(acc, a, b);
        BARRIER;

        // p7: reads buf1 a47; stage Bh0(t+3)->buf1 B-half (buf1-B reads done
        //     at p6's LGKM0, published by p6's barrier)
        #pragma unroll
        for (int m = 0; m < 4; ++m) { a[m][0] = RDA(1, m + 4, 0); a[m][1] = RDA(1, m + 4, 1); }
        STAGE(1, Bg, 1, 0, t3);
        LGKM0;
        mfma_quad<4, 0>(acc, a, b);
        BARRIER;

        // p8: stage Bh1(t+3)->buf1; counted drain (drains A(t+2)+B(t+2) for
        //     next iter's p1) + mid barrier; MFMA; fall through to next iter
        STAGE(1, Bg, 1, 1, t3);
        VMW4;
        BARRIER;
        mfma_quad<4, 2>(acc, a, b);
    }

    // epilogue: C/D col=lane&15, row=quad*4+reg (dtype-independent layout)
    const int row0 = bm * BM2 + wr * 128 + quad * 4;
    const int col0 = bn * BN2 + wc * 64 + l16;
    #pragma unroll
    for (int ni = 0; ni < 4; ++ni) {
        const int col = col0 + ni * 16;
        const float bv = BIAS[col];
        #pragma unroll
        for (int mi = 0; mi < 8; ++mi) {
            #pragma unroll
            for (int r = 0; r < 4; ++r) {
                const int row = row0 + mi * 16 + r;
                OUT[(size_t)row * TN + col] = acc[mi][ni][r] + bv;
            }
        }
    }
}

// ---------------- Fallback: fused kernel (known-good, ws too small) ----------
__global__ __launch_bounds__(256)
void gemm_fused_fallback(const float* __restrict__ X, const int* __restrict__ QW,
                         const int* __restrict__ QZ, const float* __restrict__ SC,
                         const float* __restrict__ BIAS, float* __restrict__ OUT)
{
    __shared__ __align__(16) short As[BM * BK];
    __shared__ __align__(16) short Bs[BN * BK];

    const int tid  = threadIdx.x;
    const int lane = tid & 63;
    const int wave = tid >> 6;
    const int bm = blockIdx.x / (TN / BN);
    const int bn = blockIdx.x % (TN / BN);
    const int wm = (wave & 1) * 64;
    const int wn = (wave >> 1) * 64;
    const int quad = lane >> 4;
    const int l16  = lane & 15;

    const int a_r = tid >> 2;
    const int a_c = (tid & 3) * 8;
    const float* agp = X + (size_t)(bm * BM + a_r) * TK + a_c;
    short* alp = As + a_r * BK + a_c;

    const int b_n = tid & 127;
    const int b_p = tid >> 7;
    const int n_g = bn * BN + b_n;
    const int zsh = (n_g & 7) * 4;

    floatx4 acc[4][4];
    #pragma unroll
    for (int i = 0; i < 4; ++i)
        #pragma unroll
        for (int j = 0; j < 4; ++j)
            acc[i][j] = (floatx4){0.f, 0.f, 0.f, 0.f};

    for (int g = 0; g < NG; ++g) {
        const float s = SC[(size_t)g * TN + n_g];
        const int z = (int)(((unsigned)QZ[g * QZC + (n_g >> 3)] >> zsh) & 15u) + 1;
        const float zc = -s * (float)z;

        #pragma unroll
        for (int t = 0; t < GS / BK; ++t) {
            const int k0 = g * GS + t * BK;
            floatx4 v0 = *(const floatx4*)(agp + k0);
            floatx4 v1 = *(const floatx4*)(agp + k0 + 4);
            floatx4 v2 = *(const floatx4*)(agp + (size_t)64 * TK + k0);
            floatx4 v3 = *(const floatx4*)(agp + (size_t)64 * TK + k0 + 4);
            const unsigned q0 = (unsigned)QW[(size_t)(k0 / 8 + b_p)     * TN + n_g];
            const unsigned q1 = (unsigned)QW[(size_t)(k0 / 8 + b_p + 2) * TN + n_g];

            S8U aw0, aw1;
            aw0.u[0] = pack2(v0[0], v0[1]); aw0.u[1] = pack2(v0[2], v0[3]);
            aw0.u[2] = pack2(v1[0], v1[1]); aw0.u[3] = pack2(v1[2], v1[3]);
            aw1.u[0] = pack2(v2[0], v2[1]); aw1.u[1] = pack2(v2[2], v2[3]);
            aw1.u[2] = pack2(v3[0], v3[1]); aw1.u[3] = pack2(v3[2], v3[3]);
            *(short8*)alp = aw0.v;
            *(short8*)(alp + 64 * BK) = aw1.v;

            const unsigned qs[2] = {q0, q1};
            #pragma unroll
            for (int i = 0; i < 2; ++i) {
                const int p = b_p + i * 2;
                const unsigned q = qs[i];
                const unsigned qe = q & 0x0F0F0F0Fu;
                const unsigned qo = (q >> 4) & 0x0F0F0F0Fu;
                S8U vv;
                #pragma unroll
                for (int jj = 0; jj < 4; ++jj) {
                    const float w0 = (float)((qe >> (8 * jj)) & 0xFFu);
                    const float w1 = (float)((qo >> (8 * jj)) & 0xFFu);
                    vv.u[jj] = pack2(fmaf(w0, s, zc), fmaf(w1, s, zc));
                }
                *(short8*)(Bs + b_n * BK + p * 8) = vv.v;
            }

            __syncthreads();
            short8 af[4], bfr[4];
            #pragma unroll
            for (int i = 0; i < 4; ++i) {
                af[i]  = *(const short8*)(As + (wm + i * 16 + l16) * BK + quad * 8);
                bfr[i] = *(const short8*)(Bs + (wn + i * 16 + l16) * BK + quad * 8);
            }
            #pragma unroll
            for (int mi = 0; mi < 4; ++mi)
                #pragma unroll
                for (int ni = 0; ni < 4; ++ni)
                    acc[mi][ni] = __builtin_amdgcn_mfma_f32_16x16x32_bf16(
                        af[mi], bfr[ni], acc[mi][ni], 0, 0, 0);
            __syncthreads();
        }
    }

    const int col0 = bn * BN + wn + l16;
    const int row0 = bm * BM + wm + quad * 4;
    #pragma unroll
    for (int ni = 0; ni < 4; ++ni) {
        const int col = col0 + ni * 16;
        const float bv = BIAS[col];
        #pragma unroll
        for (int mi = 0; mi < 4; ++mi) {
            #pragma unroll
            for (int r = 0; r < 4; ++r) {
                const int row = row0 + mi * 16 + r;
                OUT[(size_t)row * TN + col] = acc[mi][ni][r] + bv;
            }
        }
    }
}

extern "C" void kernel_launch(void* const* d_in, const int* in_sizes, int n_in,
                              void* d_out, int out_size, void* d_ws, size_t ws_size,
                              hipStream_t stream) {
    // Resolve inputs by element count (all distinct); fall back to dict order.
    const void* px = nullptr; const void* pqw = nullptr; const void* pqz = nullptr;
    const void* psc = nullptr; const void* pbi = nullptr;
    for (int i = 0; i < n_in; ++i) {
        switch (in_sizes[i]) {
            case 16777216: px  = d_in[i]; break;  // x
            case 5636096:  pqw = d_in[i]; break;  // qweight
            case 352256:   psc = d_in[i]; break;  // scales
            case 44032:    pqz = d_in[i]; break;  // qzeros
            case 11008:    pbi = d_in[i]; break;  // bias
            default: break;                        // g_idx unused
        }
    }
    if (!px)  px  = d_in[0];
    if (!pqw) pqw = d_in[1];
    if (!pqz) pqz = d_in[2];
    if (!psc) psc = d_in[3];
    if (!pbi) pbi = d_in[5];

    if (ws_size >= WS_NEED) {
        unsigned short* Xb = (unsigned short*)d_ws;
        unsigned short* Wt = (unsigned short*)((char*)d_ws + XB_BYTES);

        conv_x<<<dim3(TM * TK / 8 / 256), 256, 0, stream>>>((const float*)px, Xb);
        dequant_w<<<dim3(NG * (TN / DQN)), 256, 0, stream>>>(
            (const int*)pqw, (const int*)pqz, (const float*)psc, Wt);
        gemm_8ph<<<dim3(GRID2), 512, 0, stream>>>(
            Xb, Wt, (const float*)pbi, (float*)d_out);
    } else {
        gemm_fused_fallback<<<dim3((TM / BM) * (TN / BN)), 256, 0, stream>>>(
            (const float*)px, (const int*)pqw, (const int*)pqz,
            (const float*)psc, (const float*)pbi, (float*)d_out);
    }
}